// Round 6
// baseline (908.035 us; speedup 1.0000x reference)
//
#include <hip/hip_runtime.h>

// LSTM: B=512, T=512, I=128, H=50, O=10, fp32.
// R10: lstm_rec — LDS-free inner loop via register h-broadcast.
//  R9 evidence: 1125 cyc/step, issue ~400 (VALUBusy 36%), stall ~700 with
//  1 wave/SIMD (all latency exposed; batch-packing can't shorten the serial
//  chain). Dominant stall: h LDS round-trip (write b16 -> in-order DS pipe
//  -> 7x read b128 ~200-250 cyc/step).
//  New h broadcast: h stays in a register. Per step: cvt own h to f16 (RTN,
//  numerically identical to old hbuf path), v_mov_dpp quad_perm(1,0,3,2)
//  fetches pair-partner (lane^1, VALU-speed, no DS), pack half2, then 25
//  v_readlane (SALU, dual-issues with VALU) broadcast pairs straight into
//  v_dot2 (SGPR operand legal). Loop: 0 DS ops. Also drops 3 zero-pad pairs
//  (25 vs 28 dot2/gate).
//  Secondary goal: push lstm below xproj's (unknown, <240us) duration so
//  xproj surfaces in next round's top-5 with its own counters — three xproj
//  rewrites have left the ~190us residual unchanged and unexplained.
//  Everything else byte-identical to R9.

#define BB 512
#define TT 512
#define II 128
#define HH 50
#define GG 200   // 4*H

typedef _Float16 half2v __attribute__((ext_vector_type(2)));
typedef _Float16 half4v __attribute__((ext_vector_type(4)));
typedef _Float16 half8v __attribute__((ext_vector_type(8)));
typedef float float4v __attribute__((ext_vector_type(4)));

#if defined(__has_builtin)
#if __has_builtin(__builtin_amdgcn_fdot2)
#define HAVE_FDOT2 1
#endif
#endif

__device__ __forceinline__ float fdot2f(half2v a, half2v b, float c) {
#ifdef HAVE_FDOT2
    return __builtin_amdgcn_fdot2(a, b, c, false);
#else
    return c + (float)a[0] * (float)b[0] + (float)a[1] * (float)b[1];
#endif
}

__device__ __forceinline__ float fsig(float x) {
    return 1.f / (1.f + __expf(-x));
}
__device__ __forceinline__ float ftanh(float x) {
    return 2.f * fsig(2.f * x) - 1.f;
}

// ---------------- Kernel 0: prep (once per launch) ----------------
// Gate permutation: gp = unit*4 + gate  <->  orig g = gate*50 + unit.
// wfrags: W_ih rows in PERMUTED order as f16 MFMA B-fragments
//         [nt 13][kc 4][lane 64][j 8]
// whh16:  W_hh rows padded to 56 f16, ORIGINAL order  [g 200][56]
// biasv:  b_ih + b_hh in PERMUTED order               [gp 200]
__global__ __launch_bounds__(256) void prep_kernel(
    const float* __restrict__ W_ih, const float* __restrict__ W_hh,
    const float* __restrict__ b_ih, const float* __restrict__ b_hh,
    _Float16* __restrict__ wfrags, _Float16* __restrict__ whh16,
    float* __restrict__ biasv)
{
    int idx = blockIdx.x * 256 + threadIdx.x;
    if (idx < 3328) {                       // 13*4*64 fragment slots
        int lane = idx & 63, kc = (idx >> 6) & 3, nt = idx >> 8;
        int gp = nt * 16 + (lane & 15);     // permuted gate index
        int k0 = kc * 32 + ((lane >> 4) & 3) * 8;
        half8v v;
        if (gp < GG) {
            int u = gp >> 2, j = gp & 3;
            const float* wr = W_ih + (size_t)(j * HH + u) * II + k0;
            #pragma unroll
            for (int q = 0; q < 8; ++q) v[q] = (_Float16)wr[q];
        } else {
            #pragma unroll
            for (int q = 0; q < 8; ++q) v[q] = (_Float16)0.f;
        }
        *(half8v*)(wfrags + (size_t)idx * 8) = v;
    } else if (idx < 3328 + 2800) {         // 200 rows * 14 quads
        int r = idx - 3328;
        int g = r / 14, j4 = r % 14;
        #pragma unroll
        for (int j = 0; j < 4; ++j) {
            int hidx = j4 * 4 + j;
            whh16[g * 56 + hidx] = (hidx < HH) ? (_Float16)W_hh[g * HH + hidx]
                                               : (_Float16)0.f;
        }
    } else if (idx < 3328 + 2800 + GG) {
        int gp = idx - 6128;
        int u = gp >> 2, j = gp & 3;
        biasv[gp] = b_ih[j * HH + u] + b_hh[j * HH + u];
    }
}

// ---------------- Kernel 1: xproj via MFMA, batch-per-block ----------------
// Block = batch b; loops ntile (=Tc/64) t-tiles. wfrags in LDS (staged once),
// A-fragments direct-to-register, next tile prefetched under MFMA.
__global__ __launch_bounds__(256) void xproj_mfma(
    const float* __restrict__ x, const _Float16* __restrict__ wfrags,
    const float* __restrict__ biasv, _Float16* __restrict__ xp16,
    int t0, int ntile)
{
    __shared__ __align__(16) _Float16 wflds[3328 * 8];   // 53248 B
    __shared__ __align__(16) _Float16 dtile[64 * GG];    // 25600 B
    __shared__ float blds[GG];                           // 800 B  -> 79.6 KB
    const int tid = threadIdx.x;
    const int b = blockIdx.x;
    const int w = tid >> 6, l = tid & 63;

    // Stage W_ih fragments (53KB) + bias once per block (linear b128, no conflicts).
    for (int s = tid; s < 3328; s += 256)
        *(float4v*)(wflds + (size_t)s * 8) = *(const float4v*)(wfrags + (size_t)s * 8);
    for (int s = tid; s < GG; s += 256) blds[s] = biasv[s];

    // Per-thread A-fragment source: row = w*16 + (l&15), 8-float chunk (l>>4)&3.
    const int row = w * 16 + (l & 15);
    const int kq = (l >> 4) & 3;
    const float* xbase = x + ((size_t)b * TT + (size_t)t0 + row) * II + kq * 8;

    // Prologue: tile 0 A-fragments (4 kc x 32B = 8 float4).
    float4 f0[4], f1[4];
    #pragma unroll
    for (int kc = 0; kc < 4; ++kc) {
        f0[kc] = *(const float4*)(xbase + kc * 32);
        f1[kc] = *(const float4*)(xbase + kc * 32 + 4);
    }
    __syncthreads();   // wflds/blds ready

    const int colb = l & 15, rq = l >> 4;

    for (int tt = 0; tt < ntile; ++tt) {
        // Convert this tile's A-regs to half8 fragments.
        half8v a[4];
        #pragma unroll
        for (int kc = 0; kc < 4; ++kc) {
            a[kc][0] = (_Float16)f0[kc].x; a[kc][1] = (_Float16)f0[kc].y;
            a[kc][2] = (_Float16)f0[kc].z; a[kc][3] = (_Float16)f0[kc].w;
            a[kc][4] = (_Float16)f1[kc].x; a[kc][5] = (_Float16)f1[kc].y;
            a[kc][6] = (_Float16)f1[kc].z; a[kc][7] = (_Float16)f1[kc].w;
        }
        // Prefetch next tile's A into regs; completes under MFMA phase.
        if (tt + 1 < ntile) {
            const float* xn = xbase + (size_t)(tt + 1) * 64 * II;
            #pragma unroll
            for (int kc = 0; kc < 4; ++kc) {
                f0[kc] = *(const float4*)(xn + kc * 32);
                f1[kc] = *(const float4*)(xn + kc * 32 + 4);
            }
        }

        float4v acc[13];
        #pragma unroll
        for (int nt = 0; nt < 13; ++nt) acc[nt] = (float4v){0.f, 0.f, 0.f, 0.f};
        #pragma unroll
        for (int kc = 0; kc < 4; ++kc) {
            #pragma unroll
            for (int nt = 0; nt < 13; ++nt) {
                half8v bf = *(const half8v*)(wflds + (size_t)(((nt * 4 + kc) * 64) + l) * 8);
                acc[nt] = __builtin_amdgcn_mfma_f32_16x16x32_f16(a[kc], bf, acc[nt], 0, 0, 0);
            }
        }

        // Protect dtile from previous tile's writeout readers, then restage.
        __syncthreads();
        #pragma unroll
        for (int nt = 0; nt < 13; ++nt) {
            int g = nt * 16 + colb;
            if (g < GG) {
                float bs = blds[g];
                #pragma unroll
                for (int reg = 0; reg < 4; ++reg)
                    dtile[(w * 16 + rq * 4 + reg) * GG + g] = (_Float16)(acc[nt][reg] + bs);
            }
        }
        __syncthreads();

        // Coalesced writeout: 64*200 f16 = 1600 x 16B contiguous.
        _Float16* outp = xp16 + ((size_t)b * ntile + tt) * 64 * GG;
        #pragma unroll
        for (int it = 0; it < 7; ++it) {
            int idx = it * 256 + tid;
            if (idx < 1600) {
                float4v v = *(const float4v*)(dtile + (size_t)idx * 8);
                *(float4v*)(outp + (size_t)idx * 8) = v;
            }
        }
    }
}

// ---------------- Kernel 2: recurrence (register h-broadcast, no loop LDS) --
#define WSTR 58   // padded row stride in f16 (29 words -> coprime with 32 banks)

__global__
__attribute__((amdgpu_flat_work_group_size(64, 64)))
__attribute__((amdgpu_waves_per_eu(1, 1)))
void lstm_rec(
    const _Float16* __restrict__ xp16, const _Float16* __restrict__ whh16,
    float* __restrict__ hs, float* __restrict__ cs, int Tc, int first)
{
    __shared__ __align__(16) _Float16 wlds[GG * WSTR];   // 23.2 KB
    const int b = blockIdx.x;
    const int k = threadIdx.x;
    const int kk = (k < HH) ? k : 0;

    // Stage W_hh (22.4 KB) into padded LDS: 1400 b128 slots, 22 per lane.
    for (int s = k; s < 1400; s += 64) {
        int g = s / 7, j = s % 7;
        float4v v = *(const float4v*)(whh16 + (size_t)g * 56 + j * 8);
        *(float4v*)(wlds + (size_t)g * WSTR + j * 8) = v;
    }

    // h, c in registers. Lanes >= HH mirror unit 0 (kk=0); their h is never
    // consumed (readlanes only target even lanes < 50).
    float c = 0.f, h = 0.f;
    if (!first) {
        c = cs[b * HH + kk];
        h = hs[b * HH + kk];
    }
    __syncthreads();   // wlds staging visibility (once)

    // Hoisted weight loads: rows kk, kk+50, kk+100, kk+150 (7 b128 each).
    // waves_per_eu(1,1): 512-VGPR budget -> resident (R7/R9: VGPR=132).
    float4v wr0[7], wr1[7], wr2[7], wr3[7];
    #pragma unroll
    for (int j = 0; j < 7; ++j) {
        wr0[j] = *(const float4v*)(wlds + (size_t)(kk      ) * WSTR + j * 8);
        wr1[j] = *(const float4v*)(wlds + (size_t)(kk +  50) * WSTR + j * 8);
        wr2[j] = *(const float4v*)(wlds + (size_t)(kk + 100) * WSTR + j * 8);
        wr3[j] = *(const float4v*)(wlds + (size_t)(kk + 150) * WSTR + j * 8);
    }

    // xp: [b][t][unit*4+gate] -> one 8B load per step, 4-deep prefetch.
    const _Float16* xpb = xp16 + (size_t)b * Tc * GG + kk * 4;
    half4v pv[4];
    #pragma unroll
    for (int d = 0; d < 4; ++d) {
        int td = (d < Tc) ? d : (Tc - 1);
        pv[d] = *(const half4v*)(xpb + (size_t)td * GG);
    }

    #pragma unroll 4
    for (int t = 0; t < Tc; ++t) {
        const int s = t & 3;
        half4v p = pv[s];
        float aI = (float)p[0];
        float aF = (float)p[1];
        float aG = (float)p[2];
        float aO = (float)p[3];

        // refill slot s for t+4; no barrier/drain anywhere -> stays in flight
        {
            int tn = t + 4; if (tn >= Tc) tn = Tc - 1;
            pv[s] = *(const half4v*)(xpb + (size_t)tn * GG);
        }

        // Register h-broadcast: cvt own h to f16 (RTN, same numerics as the
        // old hbuf path), quad_perm(1,0,3,2) swaps lane^1 partners at VALU
        // speed, pack half2. Even lane 2m then holds (h_2m, h_2m+1).
        _Float16 h16 = (_Float16)h;
        int hi = (int)__builtin_bit_cast(unsigned short, h16);
        int hsw = __builtin_amdgcn_mov_dpp(hi, 0xB1, 0xF, 0xF, true);
        int pk = hi | (hsw << 16);

        // 25 readlane broadcasts (SALU, dual-issue with the dot2 stream).
        #pragma unroll
        for (int m = 0; m < 25; ++m) {
            int sp = __builtin_amdgcn_readlane(pk, 2 * m);
            half2v hq = __builtin_bit_cast(half2v, sp);
            int j = m >> 2, q = m & 3;
            aI = fdot2f(hq, ((const half2v*)&wr0[j])[q], aI);
            aF = fdot2f(hq, ((const half2v*)&wr1[j])[q], aF);
            aG = fdot2f(hq, ((const half2v*)&wr2[j])[q], aG);
            aO = fdot2f(hq, ((const half2v*)&wr3[j])[q], aO);
        }

        float ii = fsig(aI), ff = fsig(aF), gg2 = ftanh(aG), oo = fsig(aO);
        c = ff * c + ii * gg2;
        h = oo * ftanh(c);
    }
    if (k < HH) {
        hs[b * HH + k] = h;
        cs[b * HH + k] = c;
    }
}

// ---------------- Kernel 3: FC epilogue ----------------
__global__ __launch_bounds__(256) void fc_kernel(
    const float* __restrict__ hs, const float* __restrict__ W_fc,
    const float* __restrict__ b_fc, float* __restrict__ out)
{
    int idx = blockIdx.x * blockDim.x + threadIdx.x;   // 512*10
    if (idx < BB * 10) {
        int b = idx / 10, o = idx % 10;
        float a = b_fc[o];
        #pragma unroll
        for (int kx = 0; kx < HH; ++kx)
            a += hs[b * HH + kx] * W_fc[o * HH + kx];
        out[idx] = a;
    }
}

extern "C" void kernel_launch(void* const* d_in, const int* in_sizes, int n_in,
                              void* d_out, int out_size, void* d_ws, size_t ws_size,
                              hipStream_t stream)
{
    const float* x    = (const float*)d_in[0];
    const float* W_ih = (const float*)d_in[1];
    const float* W_hh = (const float*)d_in[2];
    const float* b_ih = (const float*)d_in[3];
    const float* b_hh = (const float*)d_in[4];
    const float* W_fc = (const float*)d_in[5];
    const float* b_fc = (const float*)d_in[6];
    float* out = (float*)d_out;
    char* wsb = (char*)d_ws;

    const size_t hs_b = (size_t)BB * HH * sizeof(float);        // 102400
    const size_t wfrags_b = (size_t)13 * 4 * 64 * 8 * 2;        // 53248
    const size_t whh_b = (size_t)GG * 56 * 2;                   // 22400
    const size_t bias_b = 1024;
    const size_t fixed_b = 2 * hs_b + wfrags_b + whh_b + bias_b;

    int Tc = TT;
    while (Tc > 64 && (size_t)BB * Tc * GG * 2 + fixed_b > ws_size)
        Tc >>= 1;

    _Float16* xp16 = (_Float16*)wsb;
    char* p = wsb + (size_t)BB * Tc * GG * 2;
    float* hsbuf = (float*)p;            p += hs_b;
    float* csbuf = (float*)p;            p += hs_b;
    _Float16* wfrags = (_Float16*)p;     p += wfrags_b;
    _Float16* whh16 = (_Float16*)p;      p += whh_b;
    float* biasv = (float*)p;

    prep_kernel<<<25, 256, 0, stream>>>(W_ih, W_hh, b_ih, b_hh, wfrags, whh16, biasv);

    const int nch = TT / Tc;
    for (int j = 0; j < nch; ++j) {
        xproj_mfma<<<BB, 256, 0, stream>>>(x, wfrags, biasv, xp16, j * Tc, Tc >> 6);
        lstm_rec<<<BB, 64, 0, stream>>>(xp16, whh16, hsbuf, csbuf, Tc, j == 0);
    }
    fc_kernel<<<(BB * 10 + 255) / 256, 256, 0, stream>>>(hsbuf, W_fc, b_fc, out);
}

// Round 7
// 495.310 us; speedup vs baseline: 1.8333x; 1.8333x over previous
//
#include <hip/hip_runtime.h>

// LSTM: B=512, T=512, I=128, H=50, O=10, fp32.
// R11: MEASUREMENT ROUND. lstm_rec loop reverted to the proven R9 body
//  (240us; R10's readlane broadcast was a 2.9x regression: v_readlane is
//  VALU not SALU, sits on the serial h-chain with SGPR-forwarding hazards).
//  Change: lstm_rec is launched as 8 chunks of 64 steps (body identical;
//  h/c carried through hs/cs exactly as the existing first/carry path).
//  Purpose: each lstm dispatch ~31us, so xproj_mfma MUST surface in the
//  top-5 with its own counters. The non-lstm residual has been invariant
//  at 210-226us across THREE different xproj structures while arithmetic
//  says xproj ~40-50us — either xproj has an invisible 4x cost (counters
//  will show regime) or the residual is harness-side (top-5 all-lstm at
//  ~31us proves xproj < 31us). Either outcome is decisive.

#define BB 512
#define TT 512
#define II 128
#define HH 50
#define GG 200   // 4*H

typedef _Float16 half2v __attribute__((ext_vector_type(2)));
typedef _Float16 half4v __attribute__((ext_vector_type(4)));
typedef _Float16 half8v __attribute__((ext_vector_type(8)));
typedef float float4v __attribute__((ext_vector_type(4)));

#if defined(__has_builtin)
#if __has_builtin(__builtin_amdgcn_fdot2)
#define HAVE_FDOT2 1
#endif
#endif

__device__ __forceinline__ float fdot2f(half2v a, half2v b, float c) {
#ifdef HAVE_FDOT2
    return __builtin_amdgcn_fdot2(a, b, c, false);
#else
    return c + (float)a[0] * (float)b[0] + (float)a[1] * (float)b[1];
#endif
}

__device__ __forceinline__ float fsig(float x) {
    return 1.f / (1.f + __expf(-x));
}
__device__ __forceinline__ float ftanh(float x) {
    return 2.f * fsig(2.f * x) - 1.f;
}

// ---------------- Kernel 0: prep (once per launch) ----------------
// Gate permutation: gp = unit*4 + gate  <->  orig g = gate*50 + unit.
// wfrags: W_ih rows in PERMUTED order as f16 MFMA B-fragments
//         [nt 13][kc 4][lane 64][j 8]
// whh16:  W_hh rows padded to 56 f16, ORIGINAL order  [g 200][56]
// biasv:  b_ih + b_hh in PERMUTED order               [gp 200]
__global__ __launch_bounds__(256) void prep_kernel(
    const float* __restrict__ W_ih, const float* __restrict__ W_hh,
    const float* __restrict__ b_ih, const float* __restrict__ b_hh,
    _Float16* __restrict__ wfrags, _Float16* __restrict__ whh16,
    float* __restrict__ biasv)
{
    int idx = blockIdx.x * 256 + threadIdx.x;
    if (idx < 3328) {                       // 13*4*64 fragment slots
        int lane = idx & 63, kc = (idx >> 6) & 3, nt = idx >> 8;
        int gp = nt * 16 + (lane & 15);     // permuted gate index
        int k0 = kc * 32 + ((lane >> 4) & 3) * 8;
        half8v v;
        if (gp < GG) {
            int u = gp >> 2, j = gp & 3;
            const float* wr = W_ih + (size_t)(j * HH + u) * II + k0;
            #pragma unroll
            for (int q = 0; q < 8; ++q) v[q] = (_Float16)wr[q];
        } else {
            #pragma unroll
            for (int q = 0; q < 8; ++q) v[q] = (_Float16)0.f;
        }
        *(half8v*)(wfrags + (size_t)idx * 8) = v;
    } else if (idx < 3328 + 2800) {         // 200 rows * 14 quads
        int r = idx - 3328;
        int g = r / 14, j4 = r % 14;
        #pragma unroll
        for (int j = 0; j < 4; ++j) {
            int hidx = j4 * 4 + j;
            whh16[g * 56 + hidx] = (hidx < HH) ? (_Float16)W_hh[g * HH + hidx]
                                               : (_Float16)0.f;
        }
    } else if (idx < 3328 + 2800 + GG) {
        int gp = idx - 6128;
        int u = gp >> 2, j = gp & 3;
        biasv[gp] = b_ih[j * HH + u] + b_hh[j * HH + u];
    }
}

// ---------------- Kernel 1: xproj via MFMA, batch-per-block ----------------
// Block = batch b; loops ntile (=Tc/64) t-tiles. wfrags in LDS (staged once),
// A-fragments direct-to-register, next tile prefetched under MFMA.
__global__ __launch_bounds__(256) void xproj_mfma(
    const float* __restrict__ x, const _Float16* __restrict__ wfrags,
    const float* __restrict__ biasv, _Float16* __restrict__ xp16,
    int t0, int ntile)
{
    __shared__ __align__(16) _Float16 wflds[3328 * 8];   // 53248 B
    __shared__ __align__(16) _Float16 dtile[64 * GG];    // 25600 B
    __shared__ float blds[GG];                           // 800 B  -> 79.6 KB
    const int tid = threadIdx.x;
    const int b = blockIdx.x;
    const int w = tid >> 6, l = tid & 63;

    // Stage W_ih fragments (53KB) + bias once per block (linear b128, no conflicts).
    for (int s = tid; s < 3328; s += 256)
        *(float4v*)(wflds + (size_t)s * 8) = *(const float4v*)(wfrags + (size_t)s * 8);
    for (int s = tid; s < GG; s += 256) blds[s] = biasv[s];

    // Per-thread A-fragment source: row = w*16 + (l&15), 8-float chunk (l>>4)&3.
    const int row = w * 16 + (l & 15);
    const int kq = (l >> 4) & 3;
    const float* xbase = x + ((size_t)b * TT + (size_t)t0 + row) * II + kq * 8;

    // Prologue: tile 0 A-fragments (4 kc x 32B = 8 float4).
    float4 f0[4], f1[4];
    #pragma unroll
    for (int kc = 0; kc < 4; ++kc) {
        f0[kc] = *(const float4*)(xbase + kc * 32);
        f1[kc] = *(const float4*)(xbase + kc * 32 + 4);
    }
    __syncthreads();   // wflds/blds ready

    const int colb = l & 15, rq = l >> 4;

    for (int tt = 0; tt < ntile; ++tt) {
        // Convert this tile's A-regs to half8 fragments.
        half8v a[4];
        #pragma unroll
        for (int kc = 0; kc < 4; ++kc) {
            a[kc][0] = (_Float16)f0[kc].x; a[kc][1] = (_Float16)f0[kc].y;
            a[kc][2] = (_Float16)f0[kc].z; a[kc][3] = (_Float16)f0[kc].w;
            a[kc][4] = (_Float16)f1[kc].x; a[kc][5] = (_Float16)f1[kc].y;
            a[kc][6] = (_Float16)f1[kc].z; a[kc][7] = (_Float16)f1[kc].w;
        }
        // Prefetch next tile's A into regs; completes under MFMA phase.
        if (tt + 1 < ntile) {
            const float* xn = xbase + (size_t)(tt + 1) * 64 * II;
            #pragma unroll
            for (int kc = 0; kc < 4; ++kc) {
                f0[kc] = *(const float4*)(xn + kc * 32);
                f1[kc] = *(const float4*)(xn + kc * 32 + 4);
            }
        }

        float4v acc[13];
        #pragma unroll
        for (int nt = 0; nt < 13; ++nt) acc[nt] = (float4v){0.f, 0.f, 0.f, 0.f};
        #pragma unroll
        for (int kc = 0; kc < 4; ++kc) {
            #pragma unroll
            for (int nt = 0; nt < 13; ++nt) {
                half8v bf = *(const half8v*)(wflds + (size_t)(((nt * 4 + kc) * 64) + l) * 8);
                acc[nt] = __builtin_amdgcn_mfma_f32_16x16x32_f16(a[kc], bf, acc[nt], 0, 0, 0);
            }
        }

        // Protect dtile from previous tile's writeout readers, then restage.
        __syncthreads();
        #pragma unroll
        for (int nt = 0; nt < 13; ++nt) {
            int g = nt * 16 + colb;
            if (g < GG) {
                float bs = blds[g];
                #pragma unroll
                for (int reg = 0; reg < 4; ++reg)
                    dtile[(w * 16 + rq * 4 + reg) * GG + g] = (_Float16)(acc[nt][reg] + bs);
            }
        }
        __syncthreads();

        // Coalesced writeout: 64*200 f16 = 1600 x 16B contiguous.
        _Float16* outp = xp16 + ((size_t)b * ntile + tt) * 64 * GG;
        #pragma unroll
        for (int it = 0; it < 7; ++it) {
            int idx = it * 256 + tid;
            if (idx < 1600) {
                float4v v = *(const float4v*)(dtile + (size_t)idx * 8);
                *(float4v*)(outp + (size_t)idx * 8) = v;
            }
        }
    }
}

// ---------------- Kernel 2: recurrence (R9 body, chunked launches) --------
#define WSTR 58   // padded row stride in f16 (29 words -> coprime with 32 banks)

__global__
__attribute__((amdgpu_flat_work_group_size(64, 64)))
__attribute__((amdgpu_waves_per_eu(1, 1)))
void lstm_rec(
    const _Float16* __restrict__ xp16, const _Float16* __restrict__ whh16,
    float* __restrict__ hs, float* __restrict__ cs,
    int Tstride, int tOff, int Tch, int first)
{
    __shared__ __align__(16) _Float16 wlds[GG * WSTR];   // 23.2 KB
    __shared__ __align__(16) _Float16 hbuf[64];
    const int b = blockIdx.x;
    const int k = threadIdx.x;
    const int kk = (k < HH) ? k : 0;

    // Stage W_hh (22.4 KB) into padded LDS: 1400 b128 slots, 22 per lane.
    for (int s = k; s < 1400; s += 64) {
        int g = s / 7, j = s % 7;
        float4v v = *(const float4v*)(whh16 + (size_t)g * 56 + j * 8);
        *(float4v*)(wlds + (size_t)g * WSTR + j * 8) = v;
    }

    float c = 0.f;
    _Float16 hinit = (_Float16)0.f;
    if (!first && k < HH) {
        c = cs[b * HH + k];
        hinit = (_Float16)hs[b * HH + k];
    }
    hbuf[k] = hinit;
    __syncthreads();   // staging + init visibility (once)

    // Hoisted weight loads: rows kk, kk+50, kk+100, kk+150 (7 b128 each).
    float4v wr0[7], wr1[7], wr2[7], wr3[7];
    #pragma unroll
    for (int j = 0; j < 7; ++j) {
        wr0[j] = *(const float4v*)(wlds + (size_t)(kk      ) * WSTR + j * 8);
        wr1[j] = *(const float4v*)(wlds + (size_t)(kk +  50) * WSTR + j * 8);
        wr2[j] = *(const float4v*)(wlds + (size_t)(kk + 100) * WSTR + j * 8);
        wr3[j] = *(const float4v*)(wlds + (size_t)(kk + 150) * WSTR + j * 8);
    }

    // xp: [b][t][unit*4+gate] (t global within this xp chunk; stride Tstride).
    const _Float16* xpb = xp16 + ((size_t)b * Tstride + tOff) * GG + kk * 4;
    half4v pv[4];
    #pragma unroll
    for (int d = 0; d < 4; ++d) {
        int td = (d < Tch) ? d : (Tch - 1);
        pv[d] = *(const half4v*)(xpb + (size_t)td * GG);
    }

    // Loop-carried h fragments: initial read, then re-read at iteration
    // bottom right after the write.
    half8v hv[7];
    #pragma unroll
    for (int j = 0; j < 7; ++j) hv[j] = *(half8v*)(hbuf + j * 8);

    float hlast = 0.f;
    #pragma unroll 4
    for (int t = 0; t < Tch; ++t) {
        const int s = t & 3;
        half4v p = pv[s];
        float aI = (float)p[0];
        float aF = (float)p[1];
        float aG = (float)p[2];
        float aO = (float)p[3];

        // refill slot s for t+4; no barrier/drain anywhere -> stays in flight
        {
            int tn = t + 4; if (tn >= Tch) tn = Tch - 1;
            pv[s] = *(const half4v*)(xpb + (size_t)tn * GG);
        }

        #pragma unroll
        for (int j = 0; j < 7; ++j) {
            half2v* hp = (half2v*)&hv[j];
            const half2v* w0 = (const half2v*)&wr0[j];
            const half2v* w1 = (const half2v*)&wr1[j];
            const half2v* w2 = (const half2v*)&wr2[j];
            const half2v* w3 = (const half2v*)&wr3[j];
            #pragma unroll
            for (int q = 0; q < 4; ++q) {
                half2v hq = hp[q];
                aI = fdot2f(hq, w0[q], aI);
                aF = fdot2f(hq, w1[q], aF);
                aG = fdot2f(hq, w2[q], aG);
                aO = fdot2f(hq, w3[q], aO);
            }
        }
        float ii = fsig(aI), ff = fsig(aF), gg2 = ftanh(aG), oo = fsig(aO);
        c = ff * c + ii * gg2;
        float hn = oo * ftanh(c);

        hbuf[k] = (_Float16)hn;
        #pragma unroll
        for (int j = 0; j < 7; ++j) hv[j] = *(half8v*)(hbuf + j * 8);

        hlast = hn;
    }
    if (k < HH) {
        hs[b * HH + k] = hlast;
        cs[b * HH + k] = c;
    }
}

// ---------------- Kernel 3: FC epilogue ----------------
__global__ __launch_bounds__(256) void fc_kernel(
    const float* __restrict__ hs, const float* __restrict__ W_fc,
    const float* __restrict__ b_fc, float* __restrict__ out)
{
    int idx = blockIdx.x * blockDim.x + threadIdx.x;   // 512*10
    if (idx < BB * 10) {
        int b = idx / 10, o = idx % 10;
        float a = b_fc[o];
        #pragma unroll
        for (int kx = 0; kx < HH; ++kx)
            a += hs[b * HH + kx] * W_fc[o * HH + kx];
        out[idx] = a;
    }
}

extern "C" void kernel_launch(void* const* d_in, const int* in_sizes, int n_in,
                              void* d_out, int out_size, void* d_ws, size_t ws_size,
                              hipStream_t stream)
{
    const float* x    = (const float*)d_in[0];
    const float* W_ih = (const float*)d_in[1];
    const float* W_hh = (const float*)d_in[2];
    const float* b_ih = (const float*)d_in[3];
    const float* b_hh = (const float*)d_in[4];
    const float* W_fc = (const float*)d_in[5];
    const float* b_fc = (const float*)d_in[6];
    float* out = (float*)d_out;
    char* wsb = (char*)d_ws;

    const size_t hs_b = (size_t)BB * HH * sizeof(float);        // 102400
    const size_t wfrags_b = (size_t)13 * 4 * 64 * 8 * 2;        // 53248
    const size_t whh_b = (size_t)GG * 56 * 2;                   // 22400
    const size_t bias_b = 1024;
    const size_t fixed_b = 2 * hs_b + wfrags_b + whh_b + bias_b;

    int Tc = TT;
    while (Tc > 64 && (size_t)BB * Tc * GG * 2 + fixed_b > ws_size)
        Tc >>= 1;

    _Float16* xp16 = (_Float16*)wsb;
    char* p = wsb + (size_t)BB * Tc * GG * 2;
    float* hsbuf = (float*)p;            p += hs_b;
    float* csbuf = (float*)p;            p += hs_b;
    _Float16* wfrags = (_Float16*)p;     p += wfrags_b;
    _Float16* whh16 = (_Float16*)p;      p += whh_b;
    float* biasv = (float*)p;

    prep_kernel<<<25, 256, 0, stream>>>(W_ih, W_hh, b_ih, b_hh, wfrags, whh16, biasv);

    const int nch = TT / Tc;
    for (int j = 0; j < nch; ++j) {
        xproj_mfma<<<BB, 256, 0, stream>>>(x, wfrags, biasv, xp16, j * Tc, Tc >> 6);
        // lstm in 64-step sub-chunks so each dispatch ~31us: forces
        // xproj_mfma into the rocprof top-5 (measurement round).
        for (int q = 0; q < Tc / 64; ++q) {
            lstm_rec<<<BB, 64, 0, stream>>>(xp16, whh16, hsbuf, csbuf,
                                            Tc, q * 64, 64,
                                            (j == 0 && q == 0) ? 1 : 0);
        }
    }
    fc_kernel<<<(BB * 10 + 255) / 256, 256, 0, stream>>>(hsbuf, W_fc, b_fc, out);
}